// Round 7
// baseline (8506.084 us; speedup 1.0000x reference)
//
#include <hip/hip_runtime.h>

#define T_STEPS 4096
#define M_BATCH 512
#define D_INP   11
#define N_HID   51

typedef __attribute__((ext_vector_type(8))) short bf16x8;   // MFMA A/B frag (8 bf16)
typedef __attribute__((ext_vector_type(4))) float f32x4;    // MFMA C/D frag
typedef __attribute__((ext_vector_type(4))) short s16x4;

__device__ __forceinline__ float sigmoid_fast(float v) {
    return __builtin_amdgcn_rcpf(1.0f + __expf(-v));
}
__device__ __forceinline__ float tanh_fast(float v) {
    return 2.0f * __builtin_amdgcn_rcpf(1.0f + __expf(-2.0f * v)) - 1.0f;
}
__device__ __forceinline__ ushort f2bf(float f) {          // fp32 -> bf16 RNE
    uint u = __float_as_uint(f);
    u += 0x7fffu + ((u >> 16) & 1u);
    return (ushort)(u >> 16);
}
__device__ __forceinline__ float bf2f(ushort h) {
    return __uint_as_float(((uint)h) << 16);
}

#define MFMA(A,B,C) __builtin_amdgcn_mfma_f32_16x16x32_bf16((A),(B),(C),0,0,0)

// MFMA 2-layer LSTM.  One block = 16 batch columns, grid = 32, 4 waves.
// Gate GEMM on matrix cores: A = weights (hi+lo bf16 split, PERSISTENT in
// registers), B = activations (single bf16, tiny LDS bufs).  Gate rows are
// interleaved r = 4*unit + gate, so the verified C/D layout (col=lane&15,
// row=(lane>>4)*4+reg) puts i,f,g,o of one (unit,col) in ONE lane's 4 accum
// regs -> lane-local state update.  W_lin is row 204 of the L2 weight matrix
// (K-cols 51..101), so the projection is a free MFMA output (lag 2 steps).
// L1 K-layout: k 0..11 = x (11+pad), 12..62 = h1, 63 = 0.   (2 K-tiles)
// L2 K-layout: k 0..50 = h1, 51..101 = h2, 102..127 = 0.    (4 K-tiles)
// Tile ownership (13 M-tiles each of L1/L2; MFMA/wave = 36/40/40/40):
//   w0: L1 m0-8   w1: L1 m9-12 + L2 m10-12 (incl. proj row)   w2: L2 m0-4
//   w3: L2 m5-9
// L2 lags L1 by one step (proven 2-barrier skeleton, rounds 3/5).
// NOTE round 6 bench was an infra failure (container died before running);
// this is an unmodified resubmit after a full correctness re-audit.
__attribute__((amdgpu_waves_per_eu(1, 1)))
__global__ __launch_bounds__(256)
void lstm2_mfma(const float* __restrict__ input,
                const float* __restrict__ W_ih1, const float* __restrict__ W_hh1,
                const float* __restrict__ b_ih1, const float* __restrict__ b_hh1,
                const float* __restrict__ W_ih2, const float* __restrict__ W_hh2,
                const float* __restrict__ b_ih2, const float* __restrict__ b_hh2,
                const float* __restrict__ W_lin, const float* __restrict__ b_lin,
                float* __restrict__ out)
{
    const int tid  = threadIdx.x;
    const int wid  = tid >> 6;
    const int lane = tid & 63;
    const int mr   = lane & 15;      // A row-in-tile; ALSO the lane's column (C/D col)
    const int g    = lane >> 4;      // k-group for A/B; unit offset for C/D
    const int col0 = blockIdx.x * 16;

    __shared__ __align__(16) ushort l1act[16][72];       // [col][u], h1 at slot u (k=12+u)
    __shared__ __align__(16) ushort l2act[16][136];      // [col][k], h1 k<51, h2 51..101
    __shared__ __align__(16) ushort xck[2][16][16][12];  // [buf][step][col][d] bf16 x
    __shared__ __align__(16) float  outb[16][64];        // [col][slot]
    __shared__ __align__(16) float  biasL1v[208];
    __shared__ __align__(16) float  biasL2v[208];

    // ---------------- LDS zero-init ----------------
    for (int i = tid; i < 16 * 72;  i += 256) (&l1act[0][0])[i] = 0;
    for (int i = tid; i < 16 * 136; i += 256) (&l2act[0][0])[i] = 0;
    for (int i = tid; i < 2 * 16 * 16 * 12; i += 256) (&xck[0][0][0][0])[i] = 0;
    for (int i = tid; i < 16 * 64;  i += 256) (&outb[0][0])[i] = 0.f;
    __syncthreads();

    // ---------------- bias tables ----------------
    if (tid < 208) {
        int r = tid; float b1, b2;
        if (r < 204) { int u = r >> 2, q = r & 3;
            b1 = b_ih1[q * 51 + u] + b_hh1[q * 51 + u];
            b2 = b_ih2[q * 51 + u] + b_hh2[q * 51 + u];
        } else { b1 = 0.f; b2 = (r == 204) ? b_lin[0] : 0.f; }
        biasL1v[r] = b1; biasL2v[r] = b2;
    }

    // ---------------- x chunk staging (16 steps, bf16) ----------------
    auto stage = [&](int cn) {
        #pragma unroll
        for (int i = 0; i < 11; ++i) {
            int f = i * 256 + tid;                       // 0..2815
            int s = f / 176, r2 = f - s * 176;
            int cc = r2 / 11, d = r2 - cc * 11;
            int ts = cn * 16 + s; if (ts > T_STEPS - 1) ts = T_STEPS - 1;
            xck[cn & 1][s][cc][d] =
                f2bf(input[((size_t)ts * M_BATCH + col0 + cc) * D_INP + d]);
        }
    };
    stage(0);

    // ---------------- persistent A-fragments (weights, hi+lo) ----------------
    auto wgetL1 = [&](int r, int k) -> float {
        if (r >= 204) return 0.f;
        int u = r >> 2, q = r & 3;
        if (k < 12) return (k < 11) ? W_ih1[(q * 51 + u) * 11 + k] : 0.f;
        int hu = k - 12; return (hu < 51) ? W_hh1[(q * 51 + u) * 51 + hu] : 0.f;
    };
    auto wgetL2 = [&](int r, int k) -> float {
        if (r == 204) return (k >= 51 && k < 102) ? W_lin[k - 51] : 0.f;
        if (r > 204) return 0.f;
        int u = r >> 2, q = r & 3;
        if (k < 51)  return W_ih2[(q * 51 + u) * 51 + k];
        if (k < 102) return W_hh2[(q * 51 + u) * 51 + (k - 51)];
        return 0.f;
    };
    // A layout: lane holds A[16m + mr][k], k = 32*kt + 16*(j>>2) + 4*g + (j&3)
    auto mkfragL1 = [&](int m, int kt, int ver) -> bf16x8 {
        bf16x8 fr;
        #pragma unroll
        for (int j = 0; j < 8; ++j) {
            int k = 32 * kt + 16 * (j >> 2) + 4 * g + (j & 3);
            float w = wgetL1(16 * m + mr, k);
            ushort hi = f2bf(w);
            fr[j] = (short)((ver == 0) ? hi : f2bf(w - bf2f(hi)));
        }
        return fr;
    };
    auto mkfragL2 = [&](int m, int kt, int ver) -> bf16x8 {
        bf16x8 fr;
        #pragma unroll
        for (int j = 0; j < 8; ++j) {
            int k = 32 * kt + 16 * (j >> 2) + 4 * g + (j & 3);
            float w = wgetL2(16 * m + mr, k);
            ushort hi = f2bf(w);
            fr[j] = (short)((ver == 0) ? hi : f2bf(w - bf2f(hi)));
        }
        return fr;
    };

    bf16x8 afr[40];
    f32x4  acc[9];
    float  cst[9];
    #pragma unroll
    for (int i = 0; i < 9; ++i) cst[i] = 0.f;
    const int MB = (wid == 2) ? 0 : 5;               // w2/w3 L2 tile base

    if (wid == 0) {
        #pragma unroll
        for (int m = 0; m < 9; ++m)
            #pragma unroll
            for (int kt = 0; kt < 2; ++kt)
                #pragma unroll
                for (int v = 0; v < 2; ++v)
                    afr[(m * 2 + kt) * 2 + v] = mkfragL1(m, kt, v);
    } else if (wid == 1) {
        #pragma unroll
        for (int mm = 0; mm < 4; ++mm)
            #pragma unroll
            for (int kt = 0; kt < 2; ++kt)
                #pragma unroll
                for (int v = 0; v < 2; ++v)
                    afr[(mm * 2 + kt) * 2 + v] = mkfragL1(9 + mm, kt, v);
        #pragma unroll
        for (int mm = 0; mm < 3; ++mm)
            #pragma unroll
            for (int kt = 0; kt < 4; ++kt)
                #pragma unroll
                for (int v = 0; v < 2; ++v)
                    afr[16 + (mm * 4 + kt) * 2 + v] = mkfragL2(10 + mm, kt, v);
    } else {
        #pragma unroll
        for (int mm = 0; mm < 5; ++mm)
            #pragma unroll
            for (int kt = 0; kt < 4; ++kt)
                #pragma unroll
                for (int v = 0; v < 2; ++v)
                    afr[(mm * 4 + kt) * 2 + v] = mkfragL2(MB + mm, kt, v);
    }
    __syncthreads();

    auto lstm = [&](f32x4 gg, float& cs) -> float {
        float iv = sigmoid_fast(gg.x), fv = sigmoid_fast(gg.y);
        float gv = tanh_fast(gg.z),    ov = sigmoid_fast(gg.w);
        cs = fv * cs + iv * gv;
        return ov * tanh_fast(cs);
    };

    #pragma unroll 1
    for (int t = 0; t <= T_STEPS + 1; ++t) {
        const int xb = (t >> 4) & 1, xs = t & 15;

        // B layout: lane holds B[k][mr], k = 32*kt + 16*half + 4*g + j
        auto loadB1 = [&](int kt) -> bf16x8 {
            int k0 = 32 * kt + 4 * g;
            const ushort* pa = (k0 < 12) ? &xck[xb][xs][mr][k0] : &l1act[mr][k0 - 12];
            s16x4 va = *(const s16x4*)pa;
            s16x4 vb = *(const s16x4*)&l1act[mr][k0 + 4];      // k0+16-12
            bf16x8 r;
            r[0]=va[0]; r[1]=va[1]; r[2]=va[2]; r[3]=va[3];
            r[4]=vb[0]; r[5]=vb[1]; r[6]=vb[2]; r[7]=vb[3];
            return r;
        };
        auto loadB2 = [&](int kt) -> bf16x8 {
            int k0 = 32 * kt + 4 * g;
            s16x4 va = *(const s16x4*)&l2act[mr][k0];
            s16x4 vb = *(const s16x4*)&l2act[mr][k0 + 16];
            bf16x8 r;
            r[0]=va[0]; r[1]=va[1]; r[2]=va[2]; r[3]=va[3];
            r[4]=vb[0]; r[5]=vb[1]; r[6]=vb[2]; r[7]=vb[3];
            return r;
        };

        // ================= phase A: MFMA gate GEMMs =================
        if (wid == 0) {
            bf16x8 b0 = loadB1(0), b1 = loadB1(1);
            #pragma unroll
            for (int m = 0; m < 9; ++m) {
                f32x4 a = {0.f, 0.f, 0.f, 0.f};
                a = MFMA(afr[(m*2+0)*2+0], b0, a);
                a = MFMA(afr[(m*2+0)*2+1], b0, a);
                a = MFMA(afr[(m*2+1)*2+0], b1, a);
                a = MFMA(afr[(m*2+1)*2+1], b1, a);
                acc[m] = a;
            }
        } else if (wid == 1) {
            bf16x8 b0 = loadB1(0), b1 = loadB1(1);
            bf16x8 b2f0 = loadB2(0), b2f1 = loadB2(1), b2f2 = loadB2(2), b2f3 = loadB2(3);
            #pragma unroll
            for (int mm = 0; mm < 4; ++mm) {
                f32x4 a = {0.f, 0.f, 0.f, 0.f};
                a = MFMA(afr[(mm*2+0)*2+0], b0, a);
                a = MFMA(afr[(mm*2+0)*2+1], b0, a);
                a = MFMA(afr[(mm*2+1)*2+0], b1, a);
                a = MFMA(afr[(mm*2+1)*2+1], b1, a);
                acc[mm] = a;
            }
            #pragma unroll
            for (int mm = 0; mm < 3; ++mm) {
                f32x4 a = {0.f, 0.f, 0.f, 0.f};
                a = MFMA(afr[16+(mm*4+0)*2+0], b2f0, a);
                a = MFMA(afr[16+(mm*4+0)*2+1], b2f0, a);
                a = MFMA(afr[16+(mm*4+1)*2+0], b2f1, a);
                a = MFMA(afr[16+(mm*4+1)*2+1], b2f1, a);
                a = MFMA(afr[16+(mm*4+2)*2+0], b2f2, a);
                a = MFMA(afr[16+(mm*4+2)*2+1], b2f2, a);
                a = MFMA(afr[16+(mm*4+3)*2+0], b2f3, a);
                a = MFMA(afr[16+(mm*4+3)*2+1], b2f3, a);
                acc[4 + mm] = a;
            }
        } else {
            bf16x8 b2f0 = loadB2(0), b2f1 = loadB2(1), b2f2 = loadB2(2), b2f3 = loadB2(3);
            #pragma unroll
            for (int mm = 0; mm < 5; ++mm) {
                f32x4 a = {0.f, 0.f, 0.f, 0.f};
                a = MFMA(afr[(mm*4+0)*2+0], b2f0, a);
                a = MFMA(afr[(mm*4+0)*2+1], b2f0, a);
                a = MFMA(afr[(mm*4+1)*2+0], b2f1, a);
                a = MFMA(afr[(mm*4+1)*2+1], b2f1, a);
                a = MFMA(afr[(mm*4+2)*2+0], b2f2, a);
                a = MFMA(afr[(mm*4+2)*2+1], b2f2, a);
                a = MFMA(afr[(mm*4+3)*2+0], b2f3, a);
                a = MFMA(afr[(mm*4+3)*2+1], b2f3, a);
                acc[mm] = a;
            }
        }
        __syncthreads();                              // B1

        // ================= phase B: lane-local state updates =================
        if (wid == 0) {
            #pragma unroll
            for (int m = 0; m < 9; ++m) {
                f32x4 gg = acc[m] + *(const f32x4*)&biasL1v[16 * m + 4 * g];
                float h = lstm(gg, cst[m]);
                int u = 4 * m + g;                    // <= 35
                ushort hb = f2bf(h);
                l1act[mr][u] = hb; l2act[mr][u] = hb;
            }
        } else if (wid == 1) {
            #pragma unroll
            for (int mm = 0; mm < 4; ++mm) {
                int m = 9 + mm;
                f32x4 gg = acc[mm] + *(const f32x4*)&biasL1v[16 * m + 4 * g];
                float h = lstm(gg, cst[mm]);
                int u = 4 * m + g;
                if (u < N_HID) { ushort hb = f2bf(h); l1act[mr][u] = hb; l2act[mr][u] = hb; }
            }
            #pragma unroll
            for (int mm = 0; mm < 3; ++mm) {
                int m = 10 + mm;
                f32x4 gg = acc[4 + mm] + *(const f32x4*)&biasL2v[16 * m + 4 * g];
                if (mm == 2 && g == 3) {              // projection row (out(t-2))
                    if (t >= 2) outb[mr][(t - 2) & 63] = gg.x;
                } else if (t >= 1) {
                    float h = lstm(gg, cst[4 + mm]);
                    l2act[mr][N_HID + 4 * m + g] = f2bf(h);
                }
            }
        } else {
            if (t >= 1) {
                #pragma unroll
                for (int mm = 0; mm < 5; ++mm) {
                    int m = MB + mm;
                    f32x4 gg = acc[mm] + *(const f32x4*)&biasL2v[16 * m + 4 * g];
                    float h = lstm(gg, cst[mm]);
                    l2act[mr][N_HID + 4 * m + g] = f2bf(h);   // u <= 39
                }
            }
        }

        if ((t & 31) == 2 && t >= 34) {               // coalesced out flush (32 steps)
            int tb0 = t - 34, cc = tid >> 4, j0 = (tid & 15) * 2;
            float2 v = *(const float2*)&outb[cc][(tb0 & 63) + j0];
            *(float2*)&out[(size_t)(col0 + cc) * T_STEPS + tb0 + j0] = v;
        }
        if ((t & 15) == 1 && t <= 4081) stage((t >> 4) + 1);
        __syncthreads();                              // B2
    }

    {                                                 // final 32 outputs
        int tb0 = 4064, cc = tid >> 4, j0 = (tid & 15) * 2;
        float2 v = *(const float2*)&outb[cc][(tb0 & 63) + j0];
        *(float2*)&out[(size_t)(col0 + cc) * T_STEPS + tb0 + j0] = v;
    }
}

extern "C" void kernel_launch(void* const* d_in, const int* in_sizes, int n_in,
                              void* d_out, int out_size, void* d_ws, size_t ws_size,
                              hipStream_t stream) {
    const float* input = (const float*)d_in[0];
    const float* W_ih1 = (const float*)d_in[1];
    const float* W_hh1 = (const float*)d_in[2];
    const float* b_ih1 = (const float*)d_in[3];
    const float* b_hh1 = (const float*)d_in[4];
    const float* W_ih2 = (const float*)d_in[5];
    const float* W_hh2 = (const float*)d_in[6];
    const float* b_ih2 = (const float*)d_in[7];
    const float* b_hh2 = (const float*)d_in[8];
    const float* W_lin = (const float*)d_in[9];
    const float* b_lin = (const float*)d_in[10];
    float* out = (float*)d_out;

    lstm2_mfma<<<M_BATCH / 16, 256, 0, stream>>>(
        input, W_ih1, W_hh1, b_ih1, b_hh1,
        W_ih2, W_hh2, b_ih2, b_hh2, W_lin, b_lin, out);
}

// Round 8
// 5058.403 us; speedup vs baseline: 1.6816x; 1.6816x over previous
//
#include <hip/hip_runtime.h>

#define T_STEPS 4096
#define M_BATCH 512
#define D_INP   11
#define N_HID   51
#define L1S     76      // l1act row stride (ushorts): 152B = 38 dwords, bank-stride 6 -> conflict-free
#define L2S     140     // l2act row stride (ushorts): 280B = 70 dwords, bank-stride 6 -> conflict-free

typedef __attribute__((ext_vector_type(8))) short bf16x8;   // MFMA A/B frag (8 bf16)
typedef __attribute__((ext_vector_type(4))) float f32x4;    // MFMA C/D frag
typedef __attribute__((ext_vector_type(4))) short s16x4;

__device__ __forceinline__ float sigmoid_fast(float v) {
    return __builtin_amdgcn_rcpf(1.0f + __expf(-v));
}
__device__ __forceinline__ float tanh_fast(float v) {
    return 2.0f * __builtin_amdgcn_rcpf(1.0f + __expf(-2.0f * v)) - 1.0f;
}
__device__ __forceinline__ ushort f2bf(float f) {          // fp32 -> bf16 RNE
    uint u = __float_as_uint(f);
    u += 0x7fffu + ((u >> 16) & 1u);
    return (ushort)(u >> 16);
}
__device__ __forceinline__ float bf2f(ushort h) {
    return __uint_as_float(((uint)h) << 16);
}

#define MFMA(A,B,C) __builtin_amdgcn_mfma_f32_16x16x32_bf16((A),(B),(C),0,0,0)

// MFMA 2-layer LSTM, 8-wave schedule.  One block = 16 batch columns, grid=32.
// DATAPATH is byte-identical to the round-7 PASSING kernel (hi+lo bf16 weight
// split, same A/B/C-D fragment mappings, W_lin as row 204 of L2).  Schedule
// fixes: (1) 8 waves -> 2 waves/SIMD TLP (round-7 had 1/SIMD, 60% stall);
// (2) LDS strides 76/140 ushorts -> bank-stride 6, conflict-free b64 reads
// (round-7: 2.6e7 conflicts at strides 72/136); (3) biases in registers
// (-26 ds_read/step); (4) x-staging split issue(t%16==2)/write(t%16==10) so
// HBM latency hides under compute; (5) hi/lo MFMA chains split (depth 8->4).
// Tile ownership: w0 L1 m0-4, w1 L1 m5-9, w2 L1 m10-12,
//                 w3-w6 L2 m0-2/3-5/6-8/9-11, w7 L2 m12 (incl. proj row 204).
// L2 lags L1 by one step; 2 barriers/step.
__attribute__((amdgpu_waves_per_eu(2, 2)))
__global__ __launch_bounds__(512)
void lstm2_mfma8(const float* __restrict__ input,
                 const float* __restrict__ W_ih1, const float* __restrict__ W_hh1,
                 const float* __restrict__ b_ih1, const float* __restrict__ b_hh1,
                 const float* __restrict__ W_ih2, const float* __restrict__ W_hh2,
                 const float* __restrict__ b_ih2, const float* __restrict__ b_hh2,
                 const float* __restrict__ W_lin, const float* __restrict__ b_lin,
                 float* __restrict__ out)
{
    const int tid  = threadIdx.x;
    const int wid  = tid >> 6;
    const int lane = tid & 63;
    const int mr   = lane & 15;      // A row-in-tile; also the batch column (C/D col)
    const int g    = lane >> 4;      // k-group; C/D row block
    const int col0 = blockIdx.x * 16;
    const bool isL1 = wid < 3;
    const int  m0   = isL1 ? ((wid == 0) ? 0 : (wid == 1) ? 5 : 10)
                           : (wid - 3) * 3;          // wid7 -> 12

    __shared__ __align__(16) ushort l1act[16][L1S];  // [col][u]: h1 at slot u (k=12+u)
    __shared__ __align__(16) ushort l2act[16][L2S];  // [col][k]: h1 k<51, h2 51..101
    __shared__ __align__(16) ushort xck[2][16][16][12]; // [buf][step][col][d]
    __shared__ __align__(16) float  outb[16][64];    // [col][slot]

    // ---------------- LDS zero-init ----------------
    for (int i = tid; i < 16 * L1S; i += 512) (&l1act[0][0])[i] = 0;
    for (int i = tid; i < 16 * L2S; i += 512) (&l2act[0][0])[i] = 0;
    for (int i = tid; i < 2 * 16 * 16 * 12; i += 512) (&xck[0][0][0][0])[i] = 0;
    for (int i = tid; i < 16 * 64; i += 512) (&outb[0][0])[i] = 0.f;

    // ---------------- x staging: issue-early / write-late ----------------
    float xr[6];
    auto xissue = [&](int cn) {                       // 2816 bf16 elems / chunk
        #pragma unroll
        for (int i = 0; i < 6; ++i) {
            int f = i * 512 + tid;
            if (f < 2816) {
                int s = f / 176, r2 = f - s * 176;
                int cc = r2 / 11, d = r2 - cc * 11;
                int ts = cn * 16 + s; if (ts > T_STEPS - 1) ts = T_STEPS - 1;
                xr[i] = input[((size_t)ts * M_BATCH + col0 + cc) * D_INP + d];
            }
        }
    };
    auto xwrite = [&](int cn) {
        #pragma unroll
        for (int i = 0; i < 6; ++i) {
            int f = i * 512 + tid;
            if (f < 2816) {
                int s = f / 176, r2 = f - s * 176;
                int cc = r2 / 11, d = r2 - cc * 11;
                xck[cn & 1][s][cc][d] = f2bf(xr[i]);
            }
        }
    };

    // ---------------- persistent A-fragments (weights, hi+lo) ----------------
    auto wgetL1 = [&](int r, int k) -> float {
        if (r >= 204) return 0.f;
        int u = r >> 2, q = r & 3;
        if (k < 12) return (k < 11) ? W_ih1[(q * 51 + u) * 11 + k] : 0.f;
        int hu = k - 12; return (hu < 51) ? W_hh1[(q * 51 + u) * 51 + hu] : 0.f;
    };
    auto wgetL2 = [&](int r, int k) -> float {
        if (r == 204) return (k >= 51 && k < 102) ? W_lin[k - 51] : 0.f;
        if (r > 204) return 0.f;
        int u = r >> 2, q = r & 3;
        if (k < 51)  return W_ih2[(q * 51 + u) * 51 + k];
        if (k < 102) return W_hh2[(q * 51 + u) * 51 + (k - 51)];
        return 0.f;
    };
    // A layout (verified r7): lane holds A[16m+mr][k], k = 32kt + 16*(j>>2) + 4g + (j&3)
    auto mkfragL1 = [&](int m, int kt, int ver) -> bf16x8 {
        bf16x8 fr;
        #pragma unroll
        for (int j = 0; j < 8; ++j) {
            int k = 32 * kt + 16 * (j >> 2) + 4 * g + (j & 3);
            float w = wgetL1(16 * m + mr, k);
            ushort hi = f2bf(w);
            fr[j] = (short)((ver == 0) ? hi : f2bf(w - bf2f(hi)));
        }
        return fr;
    };
    auto mkfragL2 = [&](int m, int kt, int ver) -> bf16x8 {
        bf16x8 fr;
        #pragma unroll
        for (int j = 0; j < 8; ++j) {
            int k = 32 * kt + 16 * (j >> 2) + 4 * g + (j & 3);
            float w = wgetL2(16 * m + mr, k);
            ushort hi = f2bf(w);
            fr[j] = (short)((ver == 0) ? hi : f2bf(w - bf2f(hi)));
        }
        return fr;
    };

    bf16x8 afr[24];
    if (wid < 2) {
        #pragma unroll
        for (int mt = 0; mt < 5; ++mt)
            #pragma unroll
            for (int kt = 0; kt < 2; ++kt)
                #pragma unroll
                for (int v = 0; v < 2; ++v)
                    afr[(mt * 2 + kt) * 2 + v] = mkfragL1(m0 + mt, kt, v);
    } else if (wid == 2) {
        #pragma unroll
        for (int mt = 0; mt < 3; ++mt)
            #pragma unroll
            for (int kt = 0; kt < 2; ++kt)
                #pragma unroll
                for (int v = 0; v < 2; ++v)
                    afr[(mt * 2 + kt) * 2 + v] = mkfragL1(m0 + mt, kt, v);
    } else if (wid < 7) {
        #pragma unroll
        for (int mt = 0; mt < 3; ++mt)
            #pragma unroll
            for (int kt = 0; kt < 4; ++kt)
                #pragma unroll
                for (int v = 0; v < 2; ++v)
                    afr[(mt * 4 + kt) * 2 + v] = mkfragL2(m0 + mt, kt, v);
    } else {
        #pragma unroll
        for (int kt = 0; kt < 4; ++kt)
            #pragma unroll
            for (int v = 0; v < 2; ++v)
                afr[kt * 2 + v] = mkfragL2(12, kt, v);
    }

    // ---------------- biases in registers (rows 16m+4g..+3 = unit 4m+g) ----------------
    f32x4 br[5];
    #pragma unroll
    for (int mt = 0; mt < 5; ++mt) {
        int u = 4 * (m0 + mt) + g;
        f32x4 b = {0.f, 0.f, 0.f, 0.f};
        if (u < N_HID) {
            #pragma unroll
            for (int q = 0; q < 4; ++q)
                b[q] = isL1 ? (b_ih1[q * 51 + u] + b_hh1[q * 51 + u])
                            : (b_ih2[q * 51 + u] + b_hh2[q * 51 + u]);
        } else if (!isL1 && u == N_HID) {
            b[0] = b_lin[0];                           // proj row 204
        }
        br[mt] = b;
    }

    f32x4 acc[5];
    float cst[5];
    #pragma unroll
    for (int i = 0; i < 5; ++i) cst[i] = 0.f;

    auto lstm = [&](f32x4 gg, float& cs) -> float {
        float iv = sigmoid_fast(gg.x), fv = sigmoid_fast(gg.y);
        float gv = tanh_fast(gg.z),    ov = sigmoid_fast(gg.w);
        cs = fv * cs + iv * gv;
        return ov * tanh_fast(cs);
    };

    // stage chunk 0 and sync
    xissue(0); xwrite(0);
    __syncthreads();

    #pragma unroll 1
    for (int t = 0; t <= T_STEPS + 1; ++t) {
        const int xb = (t >> 4) & 1, xs = t & 15;

        if ((t & 15) == 2 && t <= T_STEPS - 14) xissue((t >> 4) + 1);

        // B layout (verified r7): lane holds B[k][mr], k = 32kt + 16*(j>>2) + 4g + (j&3)
        auto loadB1 = [&](int kt) -> bf16x8 {
            int k0 = 32 * kt + 4 * g;
            const ushort* pa = (k0 < 12) ? &xck[xb][xs][mr][k0] : &l1act[mr][k0 - 12];
            s16x4 va = *(const s16x4*)pa;
            s16x4 vb = *(const s16x4*)&l1act[mr][k0 + 4];     // k0+16-12
            bf16x8 r;
            r[0]=va[0]; r[1]=va[1]; r[2]=va[2]; r[3]=va[3];
            r[4]=vb[0]; r[5]=vb[1]; r[6]=vb[2]; r[7]=vb[3];
            return r;
        };
        auto loadB2 = [&](int kt) -> bf16x8 {
            int k0 = 32 * kt + 4 * g;
            s16x4 va = *(const s16x4*)&l2act[mr][k0];
            s16x4 vb = *(const s16x4*)&l2act[mr][k0 + 16];
            bf16x8 r;
            r[0]=va[0]; r[1]=va[1]; r[2]=va[2]; r[3]=va[3];
            r[4]=vb[0]; r[5]=vb[1]; r[6]=vb[2]; r[7]=vb[3];
            return r;
        };

        // ================= phase A: MFMA gate GEMMs =================
        if (isL1) {
            bf16x8 b0 = loadB1(0), b1 = loadB1(1);
            if (wid < 2) {
                #pragma unroll
                for (int mt = 0; mt < 5; ++mt) {
                    f32x4 aH = {0.f,0.f,0.f,0.f}, aL = {0.f,0.f,0.f,0.f};
                    aH = MFMA(afr[(mt*2+0)*2+0], b0, aH);
                    aH = MFMA(afr[(mt*2+1)*2+0], b1, aH);
                    aL = MFMA(afr[(mt*2+0)*2+1], b0, aL);
                    aL = MFMA(afr[(mt*2+1)*2+1], b1, aL);
                    acc[mt] = aH + aL;
                }
            } else {
                #pragma unroll
                for (int mt = 0; mt < 3; ++mt) {
                    f32x4 aH = {0.f,0.f,0.f,0.f}, aL = {0.f,0.f,0.f,0.f};
                    aH = MFMA(afr[(mt*2+0)*2+0], b0, aH);
                    aH = MFMA(afr[(mt*2+1)*2+0], b1, aH);
                    aL = MFMA(afr[(mt*2+0)*2+1], b0, aL);
                    aL = MFMA(afr[(mt*2+1)*2+1], b1, aL);
                    acc[mt] = aH + aL;
                }
            }
        } else {
            bf16x8 c0 = loadB2(0), c1 = loadB2(1), c2 = loadB2(2), c3 = loadB2(3);
            if (wid < 7) {
                #pragma unroll
                for (int mt = 0; mt < 3; ++mt) {
                    f32x4 aH = {0.f,0.f,0.f,0.f}, aL = {0.f,0.f,0.f,0.f};
                    aH = MFMA(afr[(mt*4+0)*2+0], c0, aH);
                    aH = MFMA(afr[(mt*4+1)*2+0], c1, aH);
                    aH = MFMA(afr[(mt*4+2)*2+0], c2, aH);
                    aH = MFMA(afr[(mt*4+3)*2+0], c3, aH);
                    aL = MFMA(afr[(mt*4+0)*2+1], c0, aL);
                    aL = MFMA(afr[(mt*4+1)*2+1], c1, aL);
                    aL = MFMA(afr[(mt*4+2)*2+1], c2, aL);
                    aL = MFMA(afr[(mt*4+3)*2+1], c3, aL);
                    acc[mt] = aH + aL;
                }
            } else {
                f32x4 aH = {0.f,0.f,0.f,0.f}, aL = {0.f,0.f,0.f,0.f};
                aH = MFMA(afr[0*2+0], c0, aH);
                aH = MFMA(afr[1*2+0], c1, aH);
                aH = MFMA(afr[2*2+0], c2, aH);
                aH = MFMA(afr[3*2+0], c3, aH);
                aL = MFMA(afr[0*2+1], c0, aL);
                aL = MFMA(afr[1*2+1], c1, aL);
                aL = MFMA(afr[2*2+1], c2, aL);
                aL = MFMA(afr[3*2+1], c3, aL);
                acc[0] = aH + aL;
            }
        }
        __syncthreads();                              // B1

        // ================= phase B: lane-local state updates =================
        if (wid < 2) {                                // L1, u = 4m+g <= 39: no guard
            #pragma unroll
            for (int mt = 0; mt < 5; ++mt) {
                f32x4 gg = acc[mt] + br[mt];
                float h = lstm(gg, cst[mt]);
                int u = 4 * (m0 + mt) + g;
                ushort hb = f2bf(h);
                l1act[mr][u] = hb; l2act[mr][u] = hb;
            }
        } else if (wid == 2) {                        // L1 tiles 10-12 (u up to 51)
            #pragma unroll
            for (int mt = 0; mt < 3; ++mt) {
                f32x4 gg = acc[mt] + br[mt];
                float h = lstm(gg, cst[mt]);
                int u = 4 * (10 + mt) + g;
                if (u < N_HID) { ushort hb = f2bf(h); l1act[mr][u] = hb; l2act[mr][u] = hb; }
            }
        } else if (wid < 7) {                         // L2, u <= 47
            if (t >= 1) {
                #pragma unroll
                for (int mt = 0; mt < 3; ++mt) {
                    f32x4 gg = acc[mt] + br[mt];
                    float h = lstm(gg, cst[mt]);
                    int u = 4 * (m0 + mt) + g;
                    l2act[mr][N_HID + u] = f2bf(h);
                }
            }
        } else {                                      // L2 tile 12 + proj row
            f32x4 gg = acc[0] + br[0];
            if (g == 3) {
                if (t >= 2) outb[mr][(t - 2) & 63] = gg.x;   // out(t-2), bias included
            } else if (t >= 1) {
                float h = lstm(gg, cst[0]);
                l2act[mr][N_HID + 48 + g] = f2bf(h);         // u = 48..50
            }
        }

        if ((t & 15) == 10 && t <= T_STEPS - 6) xwrite((t >> 4) + 1);

        if ((t & 31) == 2 && t >= 34) {               // coalesced out flush (32 steps)
            int tb0 = t - 34, cc = tid >> 5, j = tid & 31;
            out[(size_t)(col0 + cc) * T_STEPS + tb0 + j] = outb[cc][(tb0 + j) & 63];
        }
        __syncthreads();                              // B2
    }

    {                                                 // final 32 outputs per col
        int tb0 = 4064, cc = tid >> 5, j = tid & 31;
        out[(size_t)(col0 + cc) * T_STEPS + tb0 + j] = outb[cc][(tb0 + j) & 63];
    }
}

extern "C" void kernel_launch(void* const* d_in, const int* in_sizes, int n_in,
                              void* d_out, int out_size, void* d_ws, size_t ws_size,
                              hipStream_t stream) {
    const float* input = (const float*)d_in[0];
    const float* W_ih1 = (const float*)d_in[1];
    const float* W_hh1 = (const float*)d_in[2];
    const float* b_ih1 = (const float*)d_in[3];
    const float* b_hh1 = (const float*)d_in[4];
    const float* W_ih2 = (const float*)d_in[5];
    const float* W_hh2 = (const float*)d_in[6];
    const float* b_ih2 = (const float*)d_in[7];
    const float* b_hh2 = (const float*)d_in[8];
    const float* W_lin = (const float*)d_in[9];
    const float* b_lin = (const float*)d_in[10];
    float* out = (float*)d_out;

    lstm2_mfma8<<<M_BATCH / 16, 512, 0, stream>>>(
        input, W_ih1, W_hh1, b_ih1, b_hh1,
        W_ih2, W_hh2, b_ih2, b_hh2, W_lin, b_lin, out);
}